// Round 5
// baseline (909.891 us; speedup 1.0000x reference)
//
#include <hip/hip_runtime.h>
#include <hip/hip_bf16.h>
#include <stdint.h>

// Problem constants (fixed by reference setup_inputs)
#define T_TOK 4096      // B*S
#define DIM   1024      // d_model (K of the GEMM)
#define VOC   50257     // vocab
#define NBLK  786       // ceil(VOC/64) n-blocks of 64 vocab rows
#define NKS   8         // DIM/128 K-steps
#define RSL   8         // k_red slices

// XqT tiled layout: for 16-row panel p, K-step s, the 2 KB frag-block at
// (p*8+s)*2048 holds, at l*32 + b (l=0..63, b=0..31):
//   byte A[row = p*16 + (l&15)][k = s*128 + (l>>4)*32 + b]
#define FRAGB  2048
#define PANB   16384    // 8 steps * 2048

#define WSCALE 64.0f
#define INV_WSCALE 0.015625f

typedef __attribute__((ext_vector_type(8))) int  i32x8;   // fp8 A/B frag (32 B)
typedef __attribute__((ext_vector_type(4))) float f32x4;

__device__ __forceinline__ uint32_t pk4_fp8(float a, float b, float c, float d) {
  int u = 0;
  u = __builtin_amdgcn_cvt_pk_fp8_f32(a, b, u, false);
  u = __builtin_amdgcn_cvt_pk_fp8_f32(c, d, u, true);
  return (uint32_t)u;
}

__device__ __forceinline__ i32x8 ld32(const uint8_t* p) {
  const int4 lo = *(const int4*)p;          // global_load_dwordx4
  const int4 hi = *(const int4*)(p + 16);   // global_load_dwordx4
  i32x8 r;
  r[0] = lo.x; r[1] = lo.y; r[2] = lo.z; r[3] = lo.w;
  r[4] = hi.x; r[5] = hi.y; r[6] = hi.z; r[7] = hi.w;
  return r;
}

__device__ __forceinline__ i32x8 ld_lds(const uint8_t* p) {
  // two-half frag layout: 16 B at p (ds_read_b128), 16 B at p+1024
  const int4 lo = *(const int4*)p;
  const int4 hi = *(const int4*)(p + 1024);
  i32x8 r;
  r[0] = lo.x; r[1] = lo.y; r[2] = lo.z; r[3] = lo.w;
  r[4] = hi.x; r[5] = hi.y; r[6] = hi.z; r[7] = hi.w;
  return r;
}

// ---------------------------------------------------------------- kernel A1:
// single-block deterministic compaction scan.
__global__ void k_scan(const int* __restrict__ masks, const int* __restrict__ targets,
                       int* __restrict__ hdr, int* __restrict__ cidx, int* __restrict__ tgtc) {
  __shared__ int cnt[256];
  const int tid = threadIdx.x;
  const int base = tid * 16;
  int c = 0;
  #pragma unroll
  for (int i = 0; i < 16; i++) c += (masks[base + i] != 0) ? 1 : 0;
  cnt[tid] = c;
  __syncthreads();
  for (int off = 1; off < 256; off <<= 1) {
    int add = (tid >= off) ? cnt[tid - off] : 0;
    __syncthreads();
    cnt[tid] += add;
    __syncthreads();
  }
  int start = cnt[tid] - c;  // exclusive prefix
  for (int i = 0; i < 16; i++) {
    int t = base + i;
    if (masks[t] != 0) { cidx[start] = t; tgtc[start] = targets[t]; start++; }
  }
  if (tid == 255) hdr[0] = cnt[255];                 // n_valid
}

// ---------------------------------------------------------------- kernel A2:
// gather valid tokens, fp32 -> fp8 e4m3, tiled layout (zeros for pad slots).
// Block = one token row (coalesced 4 KB read), 4-B tiled stores.
__global__ void k_xconv(const float* __restrict__ X, const int* __restrict__ hdr,
                        const int* __restrict__ cidx, uint8_t* __restrict__ XqT) {
  const int c4 = blockIdx.x * 256 + threadIdx.x;   // < T_TOK*DIM/4 = 1048576
  const int slot = c4 >> 8;                        // compacted token slot
  const int kq   = c4 & 255;                       // float4 index within row
  const int p = slot >> 4, rlo = slot & 15;
  const int s = kq >> 5;
  const int w128 = kq & 31;
  const int q = w128 >> 3;
  const int b = (w128 & 7) * 4;
  const int l = q * 16 + rlo;
  const int nv = hdr[0];
  uint32_t o = 0;
  if (slot < nv) {
    const float4 v = *(const float4*)(X + (size_t)cidx[slot] * DIM + (size_t)kq * 4);
    o = pk4_fp8(v.x, v.y, v.z, v.w);
  }
  *(uint32_t*)(XqT + (size_t)(p * 8 + s) * 2048 + l * 32 + b) = o;
}

// ---------------------------------------------------------------- kernel G:
// FUSED conversion + GEMM v4: barrier/atomic-free m-loop with the proven
// round-1 4x4 wave tile. Grid = 786 n-blocks of 64 vocab rows.
// Phase 1: read W slice fp32 ONCE (coalesced 256 KB), fp8-convert into 64-KB
//          LDS frag buffer. ONE barrier total.
// Phase 2: m-loop; each of 4 waves owns 64 DISTINCT tokens x 64 cols per
//          iter (block = 256 tokens/iter, mloops = ceil(nv/256)).
//          B frags re-read from LDS only ONCE per 64 tokens (4x less LDS
//          traffic/token than v3: LDS/MFMA ratio 0.7, MFMA-bound), A frags
//          register-direct from XqT (L2/L3-hot), both double-buffered.
//          16 MFMAs per half-step hide the 8 loads' latency.
//          Per-token (Se,Sl) partials -> private per-block buffer, plain
//          float4 stores: NO atomics, NO __syncthreads in the loop.
__global__ __launch_bounds__(256) void k_gemm(
    const uint8_t* __restrict__ XqT, const float* __restrict__ W,
    const int* __restrict__ hdr, const int* __restrict__ tgtc,
    float* __restrict__ tlog, float* __restrict__ Pse, float* __restrict__ Psl) {
  __shared__ __align__(16) uint8_t Blds[65536];

  const int bid = blockIdx.x;
  const int v0  = bid * 64;              // first vocab row of this block
  const int tid = threadIdx.x;
  const int w    = tid >> 6;
  const int lane = tid & 63;
  const int quad = lane >> 4;
  const int l15  = lane & 15;

  const int nv = hdr[0];
  const int mloops = (nv + 255) >> 8;    // 256 tokens per block-iter

  // ---- phase 1: W fp32 -> fp8 into LDS (two-half frag layout) ----
  {
    const int s    = tid >> 5;
    const int half = (tid & 4) ? 1024 : 0;
    const int sub  = (tid >> 3) & 3;
    const int b4   = (tid & 3) * 4;
    #pragma unroll 8
    for (int r = 0; r < 64; r++) {
      const int row = v0 + r;
      uint32_t o = 0;
      if (row < VOC) {
        const float4 v = *(const float4*)(W + (size_t)row * DIM + (size_t)tid * 4);
        o = pk4_fp8(v.x * WSCALE, v.y * WSCALE, v.z * WSCALE, v.w * WSCALE);
      }
      const int fb = (r >> 4) * 8 + s;
      const int l  = sub * 16 + (r & 15);
      *(uint32_t*)(Blds + fb * 2048 + half + l * 16 + b4) = o;
    }
  }
  __syncthreads();

  const int sc1 = 0x7F7F7F7F;   // e8m0 127 = 2^0 -> scale 1.0
  const uint8_t* pA = XqT + lane * 32;          // + panel*PANB + s*FRAGB
  const uint8_t* pB = Blds + lane * 16;         // + (p*8+s)*2048 (+1024 hi)
  float* myPse = Pse + (size_t)bid * T_TOK;
  float* myPsl = Psl + (size_t)bid * T_TOK;

  i32x8 a0[4], a1[4], B0[4], B1[4];
  #pragma unroll
  for (int i = 0; i < 4; i++) {
    a0[i] = ld32(pA + (size_t)(w * 4 + i) * PANB);     // mt=0, s=0
    B0[i] = ld_lds(pB + (i * 8) * 2048);               // s=0
  }

  // ---- phase 2: m-loop (no barriers, no atomics) ----
  for (int mt = 0; mt < mloops; mt++) {
    const size_t mb = (size_t)(mt * 16 + w * 4) * PANB;

    f32x4 acc[4][4];
    #pragma unroll
    for (int mi = 0; mi < 4; mi++)
      #pragma unroll
      for (int ni = 0; ni < 4; ni++) { f32x4 z = {0.f, 0.f, 0.f, 0.f}; acc[mi][ni] = z; }

    #pragma unroll
    for (int s = 0; s < NKS; s += 2) {
      // prefetch step s+1
      #pragma unroll
      for (int i = 0; i < 4; i++) {
        B1[i] = ld_lds(pB + (i * 8 + s + 1) * 2048);
        a1[i] = ld32(pA + mb + (size_t)i * PANB + (s + 1) * FRAGB);
      }
      #pragma unroll
      for (int mi = 0; mi < 4; mi++)
        #pragma unroll
        for (int ni = 0; ni < 4; ni++)
          acc[mi][ni] = __builtin_amdgcn_mfma_scale_f32_16x16x128_f8f6f4(
              a0[mi], B0[ni], acc[mi][ni], 0, 0, 0, sc1, 0, sc1);
      // prefetch step s+2 (or next m-strip's s=0 on wrap)
      if (s + 2 < NKS) {
        #pragma unroll
        for (int i = 0; i < 4; i++) {
          B0[i] = ld_lds(pB + (i * 8 + s + 2) * 2048);
          a0[i] = ld32(pA + mb + (size_t)i * PANB + (s + 2) * FRAGB);
        }
      } else {
        const size_t nmb = (mt + 1 < mloops) ? (size_t)((mt + 1) * 16 + w * 4) * PANB : mb;
        #pragma unroll
        for (int i = 0; i < 4; i++) {
          B0[i] = ld_lds(pB + (i * 8) * 2048);
          a0[i] = ld32(pA + nmb + (size_t)i * PANB);
        }
      }
      #pragma unroll
      for (int mi = 0; mi < 4; mi++)
        #pragma unroll
        for (int ni = 0; ni < 4; ni++)
          acc[mi][ni] = __builtin_amdgcn_mfma_scale_f32_16x16x128_f8f6f4(
              a1[mi], B1[ni], acc[mi][ni], 0, 0, 0, sc1, 0, sc1);
    }

    // ---- epilogue (per mi, small live set): D col(vocab)=l15 in panel ni,
    // row(token) = quad*4 + r within the 16-row m-frag. ----
    #pragma unroll
    for (int mi = 0; mi < 4; mi++) {
      const int trow = mt * 256 + w * 64 + mi * 16 + quad * 4;  // first of 4
      const int4 t4 = *(const int4*)&tgtc[trow];
      const int tg[4] = {t4.x, t4.y, t4.z, t4.w};
      float rse[4] = {0.f, 0.f, 0.f, 0.f};
      float rsl[4] = {0.f, 0.f, 0.f, 0.f};
      #pragma unroll
      for (int ni = 0; ni < 4; ni++) {
        const int vcol = v0 + ni * 16 + l15;
        if (vcol < VOC) {
          #pragma unroll
          for (int r = 0; r < 4; r++) {
            const float x = acc[mi][ni][r] * INV_WSCALE;
            rse[r] += __expf(x);
            rsl[r] += x;
            if (vcol == tg[r]) tlog[trow + r] = x;
          }
        }
      }
      #pragma unroll
      for (int off = 1; off < 16; off <<= 1)
        #pragma unroll
        for (int r = 0; r < 4; r++) {
          rse[r] += __shfl_xor(rse[r], off, 16);
          rsl[r] += __shfl_xor(rsl[r], off, 16);
        }
      if (l15 == 0) {
        *(float4*)&myPse[trow] = make_float4(rse[0], rse[1], rse[2], rse[3]);
        *(float4*)&myPsl[trow] = make_float4(rsl[0], rsl[1], rsl[2], rsl[3]);
      }
    }
  }
}

// ---------------------------------------------------------------- kernel R:
// column-reduce the 786 per-block partials -> 8 slice-partials. 2D grid
// (16 x 8): block (x,y) sums its ~98 b-rows for 256 tokens (coalesced).
__global__ void k_red(const int* __restrict__ hdr, const float* __restrict__ Pse,
                      const float* __restrict__ Psl, float* __restrict__ Se8,
                      float* __restrict__ Sl8) {
  const int t = blockIdx.x * 256 + threadIdx.x;
  const int y = blockIdx.y;
  const int b0 = (y * NBLK) / RSL;
  const int b1 = ((y + 1) * NBLK) / RSL;
  float se = 0.f, sl = 0.f;
  #pragma unroll 4
  for (int b = b0; b < b1; b++) {
    se += Pse[(size_t)b * T_TOK + t];
    sl += Psl[(size_t)b * T_TOK + t];
  }
  Se8[(size_t)y * T_TOK + t] = se;
  Sl8[(size_t)y * T_TOK + t] = sl;
}

// ---------------------------------------------------------------- kernel D:
// single block: per-token lse + loss reduction (sums the 8 slices inline).
__global__ void k_final(const int* __restrict__ hdr, const float* __restrict__ Se8,
                        const float* __restrict__ Sl8, const float* __restrict__ tlog,
                        float* __restrict__ out) {
  __shared__ float rn[256], rs[256];
  const int tid = threadIdx.x;
  const int nv = hdr[0];
  float nll = 0.f, slg = 0.f;
  for (int t = tid; t < nv; t += 256) {
    float se = 0.f, sl = 0.f;
    #pragma unroll
    for (int y = 0; y < RSL; y++) {
      se += Se8[(size_t)y * T_TOK + t];
      sl += Sl8[(size_t)y * T_TOK + t];
    }
    const float lse = logf(se);                 // shift-0 lse: sums ~6e4, safe
    nll += lse - tlog[t];
    slg += sl - (float)VOC * lse;
  }
  rn[tid] = nll; rs[tid] = slg;
  __syncthreads();
  for (int off = 128; off > 0; off >>= 1) {
    if (tid < off) { rn[tid] += rn[tid + off]; rs[tid] += rs[tid + off]; }
    __syncthreads();
  }
  if (tid == 0) {
    const float fnv = (float)nv;
    out[0] = 0.9f * (rn[0] / fnv) - 0.1f * (rs[0] / (fnv * (float)VOC));
  }
}

extern "C" void kernel_launch(void* const* d_in, const int* in_sizes, int n_in,
                              void* d_out, int out_size, void* d_ws, size_t ws_size,
                              hipStream_t stream) {
  const int*   targets = (const int*)d_in[0];
  const int*   masks   = (const int*)d_in[1];
  const float* X       = (const float*)d_in[2];
  const float* W       = (const float*)d_in[3];

  uint8_t* ws = (uint8_t*)d_ws;
  size_t off = 0;
  auto alloc = [&](size_t n) { size_t p = off; off += (n + 255) & ~(size_t)255; return p; };
  int*      hdr  = (int*)     (ws + alloc(256));
  int*      cidx = (int*)     (ws + alloc((size_t)T_TOK * 4));
  int*      tgtc = (int*)     (ws + alloc((size_t)T_TOK * 4));
  float*    tlog = (float*)   (ws + alloc((size_t)T_TOK * 4));
  float*    Se8  = (float*)   (ws + alloc((size_t)RSL * T_TOK * 4));
  float*    Sl8  = (float*)   (ws + alloc((size_t)RSL * T_TOK * 4));
  uint8_t*  XqT  = (uint8_t*) (ws + alloc((size_t)T_TOK * DIM));
  float*    Pse  = (float*)   (ws + alloc((size_t)NBLK * T_TOK * 4));
  float*    Psl  = (float*)   (ws + alloc((size_t)NBLK * T_TOK * 4));
  // total ~30 MB of workspace

  k_scan<<<dim3(1), dim3(256), 0, stream>>>(masks, targets, hdr, cidx, tgtc);
  k_xconv<<<dim3(T_TOK * DIM / 4 / 256), dim3(256), 0, stream>>>(X, hdr, cidx, XqT);
  k_gemm<<<dim3(NBLK), dim3(256), 0, stream>>>(XqT, W, hdr, tgtc, tlog, Pse, Psl);
  k_red<<<dim3(T_TOK / 256, RSL), dim3(256), 0, stream>>>(hdr, Pse, Psl, Se8, Sl8);
  k_final<<<dim3(1), dim3(256), 0, stream>>>(hdr, Se8, Sl8, tlog, (float*)d_out);
}

// Round 6
// 862.001 us; speedup vs baseline: 1.0556x; 1.0556x over previous
//
#include <hip/hip_runtime.h>
#include <hip/hip_bf16.h>
#include <stdint.h>

// Problem constants (fixed by reference setup_inputs)
#define T_TOK 4096      // B*S
#define DIM   1024      // d_model (K of the GEMM)
#define VOC   50257     // vocab
#define NBLK  786       // ceil(VOC/64) n-blocks of 64 vocab rows
#define NKS   8         // DIM/128 K-steps
#define RSL   8         // k_red slices

// XqT tiled layout: for 16-row panel p, K-step s, the 2 KB frag-block at
// (p*8+s)*2048 holds, at l*32 + b (l=0..63, b=0..31):
//   byte A[row = p*16 + (l&15)][k = s*128 + (l>>4)*32 + b]
#define FRAGB  2048
#define PANB   16384    // 8 steps * 2048

#define WSCALE 64.0f
#define INV_WSCALE 0.015625f

typedef __attribute__((ext_vector_type(8))) int  i32x8;   // fp8 A/B frag (32 B)
typedef __attribute__((ext_vector_type(4))) float f32x4;

__device__ __forceinline__ uint32_t pk4_fp8(float a, float b, float c, float d) {
  int u = 0;
  u = __builtin_amdgcn_cvt_pk_fp8_f32(a, b, u, false);
  u = __builtin_amdgcn_cvt_pk_fp8_f32(c, d, u, true);
  return (uint32_t)u;
}

__device__ __forceinline__ i32x8 ld32(const uint8_t* p) {
  const int4 lo = *(const int4*)p;          // global_load_dwordx4
  const int4 hi = *(const int4*)(p + 16);   // global_load_dwordx4
  i32x8 r;
  r[0] = lo.x; r[1] = lo.y; r[2] = lo.z; r[3] = lo.w;
  r[4] = hi.x; r[5] = hi.y; r[6] = hi.z; r[7] = hi.w;
  return r;
}

__device__ __forceinline__ i32x8 ld_lds(const uint8_t* p) {
  // two-half frag layout: 16 B at p (ds_read_b128), 16 B at p+1024
  const int4 lo = *(const int4*)p;
  const int4 hi = *(const int4*)(p + 1024);
  i32x8 r;
  r[0] = lo.x; r[1] = lo.y; r[2] = lo.z; r[3] = lo.w;
  r[4] = hi.x; r[5] = hi.y; r[6] = hi.z; r[7] = hi.w;
  return r;
}

// ---------------------------------------------------------------- kernel A1:
// single-block deterministic compaction scan.
__global__ void k_scan(const int* __restrict__ masks, const int* __restrict__ targets,
                       int* __restrict__ hdr, int* __restrict__ cidx, int* __restrict__ tgtc) {
  __shared__ int cnt[256];
  const int tid = threadIdx.x;
  const int base = tid * 16;
  int c = 0;
  #pragma unroll
  for (int i = 0; i < 16; i++) c += (masks[base + i] != 0) ? 1 : 0;
  cnt[tid] = c;
  __syncthreads();
  for (int off = 1; off < 256; off <<= 1) {
    int add = (tid >= off) ? cnt[tid - off] : 0;
    __syncthreads();
    cnt[tid] += add;
    __syncthreads();
  }
  int start = cnt[tid] - c;  // exclusive prefix
  for (int i = 0; i < 16; i++) {
    int t = base + i;
    if (masks[t] != 0) { cidx[start] = t; tgtc[start] = targets[t]; start++; }
  }
  if (tid == 255) hdr[0] = cnt[255];                 // n_valid
}

// ---------------------------------------------------------------- kernel A2:
// gather valid tokens, fp32 -> fp8 e4m3, tiled layout (zeros for pad slots).
// Thread = one float4 (coalesced 1 KB/wave reads, 4-B tiled stores).
__global__ void k_xconv(const float* __restrict__ X, const int* __restrict__ hdr,
                        const int* __restrict__ cidx, uint8_t* __restrict__ XqT) {
  const int c4 = blockIdx.x * 256 + threadIdx.x;   // < T_TOK*DIM/4 = 1048576
  const int slot = c4 >> 8;                        // compacted token slot
  const int kq   = c4 & 255;                       // float4 index within row
  const int p = slot >> 4, rlo = slot & 15;
  const int s = kq >> 5;
  const int w128 = kq & 31;
  const int q = w128 >> 3;
  const int b = (w128 & 7) * 4;
  const int l = q * 16 + rlo;
  const int nv = hdr[0];
  uint32_t o = 0;
  if (slot < nv) {
    const float4 v = *(const float4*)(X + (size_t)cidx[slot] * DIM + (size_t)kq * 4);
    o = pk4_fp8(v.x, v.y, v.z, v.w);
  }
  *(uint32_t*)(XqT + (size_t)(p * 8 + s) * 2048 + l * 32 + b) = o;
}

// ---------------------------------------------------------------- kernel G:
// FUSED conversion + GEMM v5: v4 with the spill source removed.
// The v4 wrap-around prefetch (next-mt a0/B0 loaded BEFORE the epilogue)
// made 64 prefetch regs + 64 acc regs + epilogue temps simultaneously live
// -> allocator exceeded the 256-reg budget -> scratch spills in the hot loop
// (round-5 evidence: WRITE_SIZE 13->134 MB, FETCH 126->590 MB, VGPR=256).
// v5: each mt loads its own s=0 frags at loop top (one exposed ~300cy L2
// latency per mt, hidden by the co-resident wave); in-step double-buffer
// pipeline unchanged. Peak liveness a0+a1+B0+B1+acc = 192 + addr ~ 220.
// NO atomics, NO __syncthreads in the m-loop.
__global__ __launch_bounds__(256) void k_gemm(
    const uint8_t* __restrict__ XqT, const float* __restrict__ W,
    const int* __restrict__ hdr, const int* __restrict__ tgtc,
    float* __restrict__ tlog, float* __restrict__ Pse, float* __restrict__ Psl) {
  __shared__ __align__(16) uint8_t Blds[65536];

  const int bid = blockIdx.x;
  const int v0  = bid * 64;              // first vocab row of this block
  const int tid = threadIdx.x;
  const int w    = tid >> 6;
  const int lane = tid & 63;
  const int quad = lane >> 4;
  const int l15  = lane & 15;

  const int nv = hdr[0];
  const int mloops = (nv + 255) >> 8;    // 256 tokens per block-iter

  // ---- phase 1: W fp32 -> fp8 into LDS (two-half frag layout) ----
  {
    const int s    = tid >> 5;
    const int half = (tid & 4) ? 1024 : 0;
    const int sub  = (tid >> 3) & 3;
    const int b4   = (tid & 3) * 4;
    #pragma unroll 8
    for (int r = 0; r < 64; r++) {
      const int row = v0 + r;
      uint32_t o = 0;
      if (row < VOC) {
        const float4 v = *(const float4*)(W + (size_t)row * DIM + (size_t)tid * 4);
        o = pk4_fp8(v.x * WSCALE, v.y * WSCALE, v.z * WSCALE, v.w * WSCALE);
      }
      const int fb = (r >> 4) * 8 + s;
      const int l  = sub * 16 + (r & 15);
      *(uint32_t*)(Blds + fb * 2048 + half + l * 16 + b4) = o;
    }
  }
  __syncthreads();

  const int sc1 = 0x7F7F7F7F;   // e8m0 127 = 2^0 -> scale 1.0
  const uint8_t* pA = XqT + lane * 32;          // + panel*PANB + s*FRAGB
  const uint8_t* pB = Blds + lane * 16;         // + (p*8+s)*2048 (+1024 hi)
  float* myPse = Pse + (size_t)bid * T_TOK;
  float* myPsl = Psl + (size_t)bid * T_TOK;

  // ---- phase 2: m-loop (no barriers, no atomics) ----
  for (int mt = 0; mt < mloops; mt++) {
    const size_t mb = (size_t)(mt * 16 + w * 4) * PANB;

    i32x8 a0[4], a1[4], B0[4], B1[4];
    #pragma unroll
    for (int i = 0; i < 4; i++) {
      a0[i] = ld32(pA + mb + (size_t)i * PANB);        // s=0
      B0[i] = ld_lds(pB + (i * 8) * 2048);             // s=0
    }

    f32x4 acc[4][4];
    #pragma unroll
    for (int mi = 0; mi < 4; mi++)
      #pragma unroll
      for (int ni = 0; ni < 4; ni++) { f32x4 z = {0.f, 0.f, 0.f, 0.f}; acc[mi][ni] = z; }

    #pragma unroll
    for (int s = 0; s < NKS; s += 2) {
      // prefetch step s+1
      #pragma unroll
      for (int i = 0; i < 4; i++) {
        B1[i] = ld_lds(pB + (i * 8 + s + 1) * 2048);
        a1[i] = ld32(pA + mb + (size_t)i * PANB + (s + 1) * FRAGB);
      }
      #pragma unroll
      for (int mi = 0; mi < 4; mi++)
        #pragma unroll
        for (int ni = 0; ni < 4; ni++)
          acc[mi][ni] = __builtin_amdgcn_mfma_scale_f32_16x16x128_f8f6f4(
              a0[mi], B0[ni], acc[mi][ni], 0, 0, 0, sc1, 0, sc1);
      // prefetch step s+2 (none past the last step: no cross-iter liveness)
      if (s + 2 < NKS) {
        #pragma unroll
        for (int i = 0; i < 4; i++) {
          B0[i] = ld_lds(pB + (i * 8 + s + 2) * 2048);
          a0[i] = ld32(pA + mb + (size_t)i * PANB + (s + 2) * FRAGB);
        }
      }
      #pragma unroll
      for (int mi = 0; mi < 4; mi++)
        #pragma unroll
        for (int ni = 0; ni < 4; ni++)
          acc[mi][ni] = __builtin_amdgcn_mfma_scale_f32_16x16x128_f8f6f4(
              a1[mi], B1[ni], acc[mi][ni], 0, 0, 0, sc1, 0, sc1);
    }

    // ---- epilogue (per mi, small live set): D col(vocab)=l15 in panel ni,
    // row(token) = quad*4 + r within the 16-row m-frag. ----
    #pragma unroll
    for (int mi = 0; mi < 4; mi++) {
      const int trow = mt * 256 + w * 64 + mi * 16 + quad * 4;  // first of 4
      const int4 t4 = *(const int4*)&tgtc[trow];
      const int tg[4] = {t4.x, t4.y, t4.z, t4.w};
      float rse[4] = {0.f, 0.f, 0.f, 0.f};
      float rsl[4] = {0.f, 0.f, 0.f, 0.f};
      #pragma unroll
      for (int ni = 0; ni < 4; ni++) {
        const int vcol = v0 + ni * 16 + l15;
        if (vcol < VOC) {
          #pragma unroll
          for (int r = 0; r < 4; r++) {
            const float x = acc[mi][ni][r] * INV_WSCALE;
            rse[r] += __expf(x);
            rsl[r] += x;
            if (vcol == tg[r]) tlog[trow + r] = x;
          }
        }
      }
      #pragma unroll
      for (int off = 1; off < 16; off <<= 1)
        #pragma unroll
        for (int r = 0; r < 4; r++) {
          rse[r] += __shfl_xor(rse[r], off, 16);
          rsl[r] += __shfl_xor(rsl[r], off, 16);
        }
      if (l15 == 0) {
        *(float4*)&myPse[trow] = make_float4(rse[0], rse[1], rse[2], rse[3]);
        *(float4*)&myPsl[trow] = make_float4(rsl[0], rsl[1], rsl[2], rsl[3]);
      }
    }
  }
}

// ---------------------------------------------------------------- kernel R:
// column-reduce the 786 per-block partials -> 8 slice-partials. 2D grid
// (16 x 8): block (x,y) sums its ~98 b-rows for 256 tokens (coalesced).
__global__ void k_red(const int* __restrict__ hdr, const float* __restrict__ Pse,
                      const float* __restrict__ Psl, float* __restrict__ Se8,
                      float* __restrict__ Sl8) {
  const int t = blockIdx.x * 256 + threadIdx.x;
  const int y = blockIdx.y;
  const int b0 = (y * NBLK) / RSL;
  const int b1 = ((y + 1) * NBLK) / RSL;
  float se = 0.f, sl = 0.f;
  #pragma unroll 4
  for (int b = b0; b < b1; b++) {
    se += Pse[(size_t)b * T_TOK + t];
    sl += Psl[(size_t)b * T_TOK + t];
  }
  Se8[(size_t)y * T_TOK + t] = se;
  Sl8[(size_t)y * T_TOK + t] = sl;
}

// ---------------------------------------------------------------- kernel D:
// single block: per-token lse + loss reduction (sums the 8 slices inline).
__global__ void k_final(const int* __restrict__ hdr, const float* __restrict__ Se8,
                        const float* __restrict__ Sl8, const float* __restrict__ tlog,
                        float* __restrict__ out) {
  __shared__ float rn[256], rs[256];
  const int tid = threadIdx.x;
  const int nv = hdr[0];
  float nll = 0.f, slg = 0.f;
  for (int t = tid; t < nv; t += 256) {
    float se = 0.f, sl = 0.f;
    #pragma unroll
    for (int y = 0; y < RSL; y++) {
      se += Se8[(size_t)y * T_TOK + t];
      sl += Sl8[(size_t)y * T_TOK + t];
    }
    const float lse = logf(se);                 // shift-0 lse: sums ~6e4, safe
    nll += lse - tlog[t];
    slg += sl - (float)VOC * lse;
  }
  rn[tid] = nll; rs[tid] = slg;
  __syncthreads();
  for (int off = 128; off > 0; off >>= 1) {
    if (tid < off) { rn[tid] += rn[tid + off]; rs[tid] += rs[tid + off]; }
    __syncthreads();
  }
  if (tid == 0) {
    const float fnv = (float)nv;
    out[0] = 0.9f * (rn[0] / fnv) - 0.1f * (rs[0] / (fnv * (float)VOC));
  }
}

extern "C" void kernel_launch(void* const* d_in, const int* in_sizes, int n_in,
                              void* d_out, int out_size, void* d_ws, size_t ws_size,
                              hipStream_t stream) {
  const int*   targets = (const int*)d_in[0];
  const int*   masks   = (const int*)d_in[1];
  const float* X       = (const float*)d_in[2];
  const float* W       = (const float*)d_in[3];

  uint8_t* ws = (uint8_t*)d_ws;
  size_t off = 0;
  auto alloc = [&](size_t n) { size_t p = off; off += (n + 255) & ~(size_t)255; return p; };
  int*      hdr  = (int*)     (ws + alloc(256));
  int*      cidx = (int*)     (ws + alloc((size_t)T_TOK * 4));
  int*      tgtc = (int*)     (ws + alloc((size_t)T_TOK * 4));
  float*    tlog = (float*)   (ws + alloc((size_t)T_TOK * 4));
  float*    Se8  = (float*)   (ws + alloc((size_t)RSL * T_TOK * 4));
  float*    Sl8  = (float*)   (ws + alloc((size_t)RSL * T_TOK * 4));
  uint8_t*  XqT  = (uint8_t*) (ws + alloc((size_t)T_TOK * DIM));
  float*    Pse  = (float*)   (ws + alloc((size_t)NBLK * T_TOK * 4));
  float*    Psl  = (float*)   (ws + alloc((size_t)NBLK * T_TOK * 4));
  // total ~30 MB of workspace

  k_scan<<<dim3(1), dim3(256), 0, stream>>>(masks, targets, hdr, cidx, tgtc);
  k_xconv<<<dim3(T_TOK * DIM / 4 / 256), dim3(256), 0, stream>>>(X, hdr, cidx, XqT);
  k_gemm<<<dim3(NBLK), dim3(256), 0, stream>>>(XqT, W, hdr, tgtc, tlog, Pse, Psl);
  k_red<<<dim3(T_TOK / 256, RSL), dim3(256), 0, stream>>>(hdr, Pse, Psl, Se8, Sl8);
  k_final<<<dim3(1), dim3(256), 0, stream>>>(hdr, Se8, Sl8, tlog, (float*)d_out);
}

// Round 7
// 815.178 us; speedup vs baseline: 1.1162x; 1.0574x over previous
//
#include <hip/hip_runtime.h>
#include <hip/hip_bf16.h>
#include <stdint.h>

// Problem constants (fixed by reference setup_inputs)
#define T_TOK 4096      // B*S
#define DIM   1024      // d_model (K of the GEMM)
#define VOC   50257     // vocab
#define NBLK  786       // ceil(VOC/64) n-blocks of 64 vocab rows
#define NKS   8         // DIM/128 K-steps
#define RSL   8         // k_red slices

// XqT tiled layout: for 16-row panel p, K-step s, the 2 KB frag-block at
// (p*8+s)*2048 holds, at l*32 + b (l=0..63, b=0..31):
//   byte A[row = p*16 + (l&15)][k = s*128 + (l>>4)*32 + b]
#define FRAGB  2048
#define PANB   16384    // 8 steps * 2048

#define WSCALE 64.0f
#define INV_WSCALE 0.015625f

typedef __attribute__((ext_vector_type(8))) int  i32x8;   // fp8 A/B frag (32 B)
typedef __attribute__((ext_vector_type(4))) float f32x4;

__device__ __forceinline__ uint32_t pk4_fp8(float a, float b, float c, float d) {
  int u = 0;
  u = __builtin_amdgcn_cvt_pk_fp8_f32(a, b, u, false);
  u = __builtin_amdgcn_cvt_pk_fp8_f32(c, d, u, true);
  return (uint32_t)u;
}

__device__ __forceinline__ i32x8 ld32(const uint8_t* p) {
  const int4 lo = *(const int4*)p;          // global_load_dwordx4
  const int4 hi = *(const int4*)(p + 16);   // global_load_dwordx4
  i32x8 r;
  r[0] = lo.x; r[1] = lo.y; r[2] = lo.z; r[3] = lo.w;
  r[4] = hi.x; r[5] = hi.y; r[6] = hi.z; r[7] = hi.w;
  return r;
}

__device__ __forceinline__ i32x8 ld_lds(const uint8_t* p) {
  // two-half frag layout: 16 B at p (ds_read_b128), 16 B at p+1024
  const int4 lo = *(const int4*)p;
  const int4 hi = *(const int4*)(p + 1024);
  i32x8 r;
  r[0] = lo.x; r[1] = lo.y; r[2] = lo.z; r[3] = lo.w;
  r[4] = hi.x; r[5] = hi.y; r[6] = hi.z; r[7] = hi.w;
  return r;
}

// ---------------------------------------------------------------- kernel A1:
// single-block deterministic compaction scan.
__global__ void k_scan(const int* __restrict__ masks, const int* __restrict__ targets,
                       int* __restrict__ hdr, int* __restrict__ cidx, int* __restrict__ tgtc) {
  __shared__ int cnt[256];
  const int tid = threadIdx.x;
  const int base = tid * 16;
  int c = 0;
  #pragma unroll
  for (int i = 0; i < 16; i++) c += (masks[base + i] != 0) ? 1 : 0;
  cnt[tid] = c;
  __syncthreads();
  for (int off = 1; off < 256; off <<= 1) {
    int add = (tid >= off) ? cnt[tid - off] : 0;
    __syncthreads();
    cnt[tid] += add;
    __syncthreads();
  }
  int start = cnt[tid] - c;  // exclusive prefix
  for (int i = 0; i < 16; i++) {
    int t = base + i;
    if (masks[t] != 0) { cidx[start] = t; tgtc[start] = targets[t]; start++; }
  }
  if (tid == 255) hdr[0] = cnt[255];                 // n_valid
}

// ---------------------------------------------------------------- kernel A2:
// gather valid tokens, fp32 -> fp8 e4m3, tiled layout (zeros for pad slots).
// Thread = one float4 (coalesced 1 KB/wave reads, 4-B tiled stores).
__global__ void k_xconv(const float* __restrict__ X, const int* __restrict__ hdr,
                        const int* __restrict__ cidx, uint8_t* __restrict__ XqT) {
  const int c4 = blockIdx.x * 256 + threadIdx.x;   // < T_TOK*DIM/4 = 1048576
  const int slot = c4 >> 8;                        // compacted token slot
  const int kq   = c4 & 255;                       // float4 index within row
  const int p = slot >> 4, rlo = slot & 15;
  const int s = kq >> 5;
  const int w128 = kq & 31;
  const int q = w128 >> 3;
  const int b = (w128 & 7) * 4;
  const int l = q * 16 + rlo;
  const int nv = hdr[0];
  uint32_t o = 0;
  if (slot < nv) {
    const float4 v = *(const float4*)(X + (size_t)cidx[slot] * DIM + (size_t)kq * 4);
    o = pk4_fp8(v.x, v.y, v.z, v.w);
  }
  *(uint32_t*)(XqT + (size_t)(p * 8 + s) * 2048 + l * 32 + b) = o;
}

// ---------------------------------------------------------------- kernel G:
// FUSED conversion + GEMM v6 = v5 + scheduler fences.
// Round-6 evidence: even with no source-level cross-iter prefetch, the
// compiler software-pipelined the m-loop (hoisted mt+1's s=0 loads above
// mt's epilogue) and re-created the spill (VGPR=256, WRITE_SIZE 102 MB).
// v6 pins the regions: sched_barrier(0) after the K-loop, and
// sched_barrier(0) + asm memory clobber at end of the m-loop body so no
// load can hoist above the epilogue's stores. In-loop live set (a0/a1/B0/
// B1 = 128, acc = 64) fits the 256-reg budget (round-1 precedent: 240).
// NO atomics, NO __syncthreads in the m-loop.
__global__ __launch_bounds__(256) void k_gemm(
    const uint8_t* __restrict__ XqT, const float* __restrict__ W,
    const int* __restrict__ hdr, const int* __restrict__ tgtc,
    float* __restrict__ tlog, float* __restrict__ Pse, float* __restrict__ Psl) {
  __shared__ __align__(16) uint8_t Blds[65536];

  const int bid = blockIdx.x;
  const int v0  = bid * 64;              // first vocab row of this block
  const int tid = threadIdx.x;
  const int w    = tid >> 6;
  const int lane = tid & 63;
  const int quad = lane >> 4;
  const int l15  = lane & 15;

  const int nv = hdr[0];
  const int mloops = (nv + 255) >> 8;    // 256 tokens per block-iter

  // ---- phase 1: W fp32 -> fp8 into LDS (two-half frag layout) ----
  {
    const int s    = tid >> 5;
    const int half = (tid & 4) ? 1024 : 0;
    const int sub  = (tid >> 3) & 3;
    const int b4   = (tid & 3) * 4;
    #pragma unroll 8
    for (int r = 0; r < 64; r++) {
      const int row = v0 + r;
      uint32_t o = 0;
      if (row < VOC) {
        const float4 v = *(const float4*)(W + (size_t)row * DIM + (size_t)tid * 4);
        o = pk4_fp8(v.x * WSCALE, v.y * WSCALE, v.z * WSCALE, v.w * WSCALE);
      }
      const int fb = (r >> 4) * 8 + s;
      const int l  = sub * 16 + (r & 15);
      *(uint32_t*)(Blds + fb * 2048 + half + l * 16 + b4) = o;
    }
  }
  __syncthreads();

  const int sc1 = 0x7F7F7F7F;   // e8m0 127 = 2^0 -> scale 1.0
  const uint8_t* pA = XqT + lane * 32;          // + panel*PANB + s*FRAGB
  const uint8_t* pB = Blds + lane * 16;         // + (p*8+s)*2048 (+1024 hi)
  float* myPse = Pse + (size_t)bid * T_TOK;
  float* myPsl = Psl + (size_t)bid * T_TOK;

  // ---- phase 2: m-loop (no barriers, no atomics) ----
  for (int mt = 0; mt < mloops; mt++) {
    const size_t mb = (size_t)(mt * 16 + w * 4) * PANB;

    i32x8 a0[4], a1[4], B0[4], B1[4];
    #pragma unroll
    for (int i = 0; i < 4; i++) {
      a0[i] = ld32(pA + mb + (size_t)i * PANB);        // s=0
      B0[i] = ld_lds(pB + (i * 8) * 2048);             // s=0
    }

    f32x4 acc[4][4];
    #pragma unroll
    for (int mi = 0; mi < 4; mi++)
      #pragma unroll
      for (int ni = 0; ni < 4; ni++) { f32x4 z = {0.f, 0.f, 0.f, 0.f}; acc[mi][ni] = z; }

    #pragma unroll
    for (int s = 0; s < NKS; s += 2) {
      // prefetch step s+1
      #pragma unroll
      for (int i = 0; i < 4; i++) {
        B1[i] = ld_lds(pB + (i * 8 + s + 1) * 2048);
        a1[i] = ld32(pA + mb + (size_t)i * PANB + (s + 1) * FRAGB);
      }
      #pragma unroll
      for (int mi = 0; mi < 4; mi++)
        #pragma unroll
        for (int ni = 0; ni < 4; ni++)
          acc[mi][ni] = __builtin_amdgcn_mfma_scale_f32_16x16x128_f8f6f4(
              a0[mi], B0[ni], acc[mi][ni], 0, 0, 0, sc1, 0, sc1);
      // prefetch step s+2 (none past the last step: no cross-iter liveness)
      if (s + 2 < NKS) {
        #pragma unroll
        for (int i = 0; i < 4; i++) {
          B0[i] = ld_lds(pB + (i * 8 + s + 2) * 2048);
          a0[i] = ld32(pA + mb + (size_t)i * PANB + (s + 2) * FRAGB);
        }
      }
      #pragma unroll
      for (int mi = 0; mi < 4; mi++)
        #pragma unroll
        for (int ni = 0; ni < 4; ni++)
          acc[mi][ni] = __builtin_amdgcn_mfma_scale_f32_16x16x128_f8f6f4(
              a1[mi], B1[ni], acc[mi][ni], 0, 0, 0, sc1, 0, sc1);
    }

    // keep the MFMA region clean: nothing from the epilogue (or later
    // iterations) may be scheduled up into the K-loop.
    __builtin_amdgcn_sched_barrier(0);

    // ---- epilogue (per mi, small live set): D col(vocab)=l15 in panel ni,
    // row(token) = quad*4 + r within the 16-row m-frag. ----
    #pragma unroll
    for (int mi = 0; mi < 4; mi++) {
      const int trow = mt * 256 + w * 64 + mi * 16 + quad * 4;  // first of 4
      const int4 t4 = *(const int4*)&tgtc[trow];
      const int tg[4] = {t4.x, t4.y, t4.z, t4.w};
      float rse[4] = {0.f, 0.f, 0.f, 0.f};
      float rsl[4] = {0.f, 0.f, 0.f, 0.f};
      #pragma unroll
      for (int ni = 0; ni < 4; ni++) {
        const int vcol = v0 + ni * 16 + l15;
        if (vcol < VOC) {
          #pragma unroll
          for (int r = 0; r < 4; r++) {
            const float x = acc[mi][ni][r] * INV_WSCALE;
            rse[r] += __expf(x);
            rsl[r] += x;
            if (vcol == tg[r]) tlog[trow + r] = x;
          }
        }
      }
      #pragma unroll
      for (int off = 1; off < 16; off <<= 1)
        #pragma unroll
        for (int r = 0; r < 4; r++) {
          rse[r] += __shfl_xor(rse[r], off, 16);
          rsl[r] += __shfl_xor(rsl[r], off, 16);
        }
      if (l15 == 0) {
        *(float4*)&myPse[trow] = make_float4(rse[0], rse[1], rse[2], rse[3]);
        *(float4*)&myPsl[trow] = make_float4(rsl[0], rsl[1], rsl[2], rsl[3]);
      }
    }

    // hard iteration boundary: next iteration's loads may not hoist above
    // this point (memory clobber orders them against the epilogue stores),
    // so cross-iteration liveness never exceeds the register budget.
    __builtin_amdgcn_sched_barrier(0);
    asm volatile("" ::: "memory");
  }
}

// ---------------------------------------------------------------- kernel R:
// column-reduce the 786 per-block partials -> 8 slice-partials. 2D grid
// (16 x 8): block (x,y) sums its ~98 b-rows for 256 tokens (coalesced).
__global__ void k_red(const int* __restrict__ hdr, const float* __restrict__ Pse,
                      const float* __restrict__ Psl, float* __restrict__ Se8,
                      float* __restrict__ Sl8) {
  const int t = blockIdx.x * 256 + threadIdx.x;
  const int y = blockIdx.y;
  const int b0 = (y * NBLK) / RSL;
  const int b1 = ((y + 1) * NBLK) / RSL;
  float se = 0.f, sl = 0.f;
  #pragma unroll 4
  for (int b = b0; b < b1; b++) {
    se += Pse[(size_t)b * T_TOK + t];
    sl += Psl[(size_t)b * T_TOK + t];
  }
  Se8[(size_t)y * T_TOK + t] = se;
  Sl8[(size_t)y * T_TOK + t] = sl;
}

// ---------------------------------------------------------------- kernel D:
// single block: per-token lse + loss reduction (sums the 8 slices inline).
__global__ void k_final(const int* __restrict__ hdr, const float* __restrict__ Se8,
                        const float* __restrict__ Sl8, const float* __restrict__ tlog,
                        float* __restrict__ out) {
  __shared__ float rn[256], rs[256];
  const int tid = threadIdx.x;
  const int nv = hdr[0];
  float nll = 0.f, slg = 0.f;
  for (int t = tid; t < nv; t += 256) {
    float se = 0.f, sl = 0.f;
    #pragma unroll
    for (int y = 0; y < RSL; y++) {
      se += Se8[(size_t)y * T_TOK + t];
      sl += Sl8[(size_t)y * T_TOK + t];
    }
    const float lse = logf(se);                 // shift-0 lse: sums ~6e4, safe
    nll += lse - tlog[t];
    slg += sl - (float)VOC * lse;
  }
  rn[tid] = nll; rs[tid] = slg;
  __syncthreads();
  for (int off = 128; off > 0; off >>= 1) {
    if (tid < off) { rn[tid] += rn[tid + off]; rs[tid] += rs[tid + off]; }
    __syncthreads();
  }
  if (tid == 0) {
    const float fnv = (float)nv;
    out[0] = 0.9f * (rn[0] / fnv) - 0.1f * (rs[0] / (fnv * (float)VOC));
  }
}

extern "C" void kernel_launch(void* const* d_in, const int* in_sizes, int n_in,
                              void* d_out, int out_size, void* d_ws, size_t ws_size,
                              hipStream_t stream) {
  const int*   targets = (const int*)d_in[0];
  const int*   masks   = (const int*)d_in[1];
  const float* X       = (const float*)d_in[2];
  const float* W       = (const float*)d_in[3];

  uint8_t* ws = (uint8_t*)d_ws;
  size_t off = 0;
  auto alloc = [&](size_t n) { size_t p = off; off += (n + 255) & ~(size_t)255; return p; };
  int*      hdr  = (int*)     (ws + alloc(256));
  int*      cidx = (int*)     (ws + alloc((size_t)T_TOK * 4));
  int*      tgtc = (int*)     (ws + alloc((size_t)T_TOK * 4));
  float*    tlog = (float*)   (ws + alloc((size_t)T_TOK * 4));
  float*    Se8  = (float*)   (ws + alloc((size_t)RSL * T_TOK * 4));
  float*    Sl8  = (float*)   (ws + alloc((size_t)RSL * T_TOK * 4));
  uint8_t*  XqT  = (uint8_t*) (ws + alloc((size_t)T_TOK * DIM));
  float*    Pse  = (float*)   (ws + alloc((size_t)NBLK * T_TOK * 4));
  float*    Psl  = (float*)   (ws + alloc((size_t)NBLK * T_TOK * 4));
  // total ~30 MB of workspace

  k_scan<<<dim3(1), dim3(256), 0, stream>>>(masks, targets, hdr, cidx, tgtc);
  k_xconv<<<dim3(T_TOK * DIM / 4 / 256), dim3(256), 0, stream>>>(X, hdr, cidx, XqT);
  k_gemm<<<dim3(NBLK), dim3(256), 0, stream>>>(XqT, W, hdr, tgtc, tlog, Pse, Psl);
  k_red<<<dim3(T_TOK / 256, RSL), dim3(256), 0, stream>>>(hdr, Pse, Psl, Se8, Sl8);
  k_final<<<dim3(1), dim3(256), 0, stream>>>(hdr, Se8, Sl8, tlog, (float*)d_out);
}

// Round 8
// 664.399 us; speedup vs baseline: 1.3695x; 1.2269x over previous
//
#include <hip/hip_runtime.h>
#include <hip/hip_bf16.h>
#include <stdint.h>

// Problem constants (fixed by reference setup_inputs)
#define T_TOK 4096      // B*S
#define DIM   1024      // d_model (K of the GEMM)
#define VOC   50257     // vocab
#define NBLK  786       // ceil(VOC/64) n-blocks of 64 vocab rows
#define NKS   8         // DIM/128 K-steps
#define RSL   8         // k_red slices

// XqT tiled layout: for 16-row panel p, K-step s, the 2 KB frag-block at
// (p*8+s)*2048 holds, at l*32 + b (l=0..63, b=0..31):
//   byte A[row = p*16 + (l&15)][k = s*128 + (l>>4)*32 + b]
#define FRAGB  2048
#define PANB   16384    // 8 steps * 2048

#define WSCALE 64.0f
#define INV_WSCALE 0.015625f

typedef __attribute__((ext_vector_type(8))) int  i32x8;   // fp8 A/B frag (32 B)
typedef __attribute__((ext_vector_type(4))) float f32x4;

__device__ __forceinline__ uint32_t pk4_fp8(float a, float b, float c, float d) {
  int u = 0;
  u = __builtin_amdgcn_cvt_pk_fp8_f32(a, b, u, false);
  u = __builtin_amdgcn_cvt_pk_fp8_f32(c, d, u, true);
  return (uint32_t)u;
}

__device__ __forceinline__ i32x8 ld32(const uint8_t* p) {
  const int4 lo = *(const int4*)p;          // global_load_dwordx4
  const int4 hi = *(const int4*)(p + 16);   // global_load_dwordx4
  i32x8 r;
  r[0] = lo.x; r[1] = lo.y; r[2] = lo.z; r[3] = lo.w;
  r[4] = hi.x; r[5] = hi.y; r[6] = hi.z; r[7] = hi.w;
  return r;
}

__device__ __forceinline__ i32x8 ld_lds(const uint8_t* p) {
  // two-half frag layout: 16 B at p (ds_read_b128), 16 B at p+1024
  const int4 lo = *(const int4*)p;
  const int4 hi = *(const int4*)(p + 1024);
  i32x8 r;
  r[0] = lo.x; r[1] = lo.y; r[2] = lo.z; r[3] = lo.w;
  r[4] = hi.x; r[5] = hi.y; r[6] = hi.z; r[7] = hi.w;
  return r;
}

// ---------------------------------------------------------------- kernel A1:
// single-block deterministic compaction scan.
__global__ void k_scan(const int* __restrict__ masks, const int* __restrict__ targets,
                       int* __restrict__ hdr, int* __restrict__ cidx, int* __restrict__ tgtc) {
  __shared__ int cnt[256];
  const int tid = threadIdx.x;
  const int base = tid * 16;
  int c = 0;
  #pragma unroll
  for (int i = 0; i < 16; i++) c += (masks[base + i] != 0) ? 1 : 0;
  cnt[tid] = c;
  __syncthreads();
  for (int off = 1; off < 256; off <<= 1) {
    int add = (tid >= off) ? cnt[tid - off] : 0;
    __syncthreads();
    cnt[tid] += add;
    __syncthreads();
  }
  int start = cnt[tid] - c;  // exclusive prefix
  for (int i = 0; i < 16; i++) {
    int t = base + i;
    if (masks[t] != 0) { cidx[start] = t; tgtc[start] = targets[t]; start++; }
  }
  if (tid == 255) hdr[0] = cnt[255];                 // n_valid
}

// ---------------------------------------------------------------- kernel A2:
// gather valid tokens, fp32 -> fp8 e4m3, tiled layout (zeros for pad slots).
// Thread = one float4 (coalesced 1 KB/wave reads, 4-B tiled stores).
__global__ void k_xconv(const float* __restrict__ X, const int* __restrict__ hdr,
                        const int* __restrict__ cidx, uint8_t* __restrict__ XqT) {
  const int c4 = blockIdx.x * 256 + threadIdx.x;   // < T_TOK*DIM/4 = 1048576
  const int slot = c4 >> 8;                        // compacted token slot
  const int kq   = c4 & 255;                       // float4 index within row
  const int p = slot >> 4, rlo = slot & 15;
  const int s = kq >> 5;
  const int w128 = kq & 31;
  const int q = w128 >> 3;
  const int b = (w128 & 7) * 4;
  const int l = q * 16 + rlo;
  const int nv = hdr[0];
  uint32_t o = 0;
  if (slot < nv) {
    const float4 v = *(const float4*)(X + (size_t)cidx[slot] * DIM + (size_t)kq * 4);
    o = pk4_fp8(v.x, v.y, v.z, v.w);
  }
  *(uint32_t*)(XqT + (size_t)(p * 8 + s) * 2048 + l * 32 + b) = o;
}

// ---------------------------------------------------------------- kernel G:
// FUSED conversion + GEMM v7: v3 structure (the only no-spill variant:
// VGPR 188, WRITE 13 MB, 434 us) widened ONE step on the token-reuse
// frontier: wave = 32 tokens x 64 cols.
// Register-budget model from rounds 4-7: data-regs + ~90 overhead must be
// < 256. v3: 96+90=186 ok. v4/v5/v6: 192+90=282 -> spill (3x proven).
// v7: a0/a1(32) + B0/B1(64) + acc(32) = 128 data -> ~220 total, fits.
// Halves v3's B-LDS traffic per token (LDS was the v3 limiter) and halves
// the per-token epilogue cost. NO atomics, NO __syncthreads in the m-loop;
// sched fences retained to forbid cross-iteration hoisting.
__global__ __launch_bounds__(256) void k_gemm(
    const uint8_t* __restrict__ XqT, const float* __restrict__ W,
    const int* __restrict__ hdr, const int* __restrict__ tgtc,
    float* __restrict__ tlog, float* __restrict__ Pse, float* __restrict__ Psl) {
  __shared__ __align__(16) uint8_t Blds[65536];

  const int bid = blockIdx.x;
  const int v0  = bid * 64;              // first vocab row of this block
  const int tid = threadIdx.x;
  const int w    = tid >> 6;
  const int lane = tid & 63;
  const int quad = lane >> 4;
  const int l15  = lane & 15;

  const int nv = hdr[0];
  const int mloops = (nv + 127) >> 7;    // 128 tokens per block-iter

  // ---- phase 1: W fp32 -> fp8 into LDS (two-half frag layout) ----
  {
    const int s    = tid >> 5;
    const int half = (tid & 4) ? 1024 : 0;
    const int sub  = (tid >> 3) & 3;
    const int b4   = (tid & 3) * 4;
    #pragma unroll 8
    for (int r = 0; r < 64; r++) {
      const int row = v0 + r;
      uint32_t o = 0;
      if (row < VOC) {
        const float4 v = *(const float4*)(W + (size_t)row * DIM + (size_t)tid * 4);
        o = pk4_fp8(v.x * WSCALE, v.y * WSCALE, v.z * WSCALE, v.w * WSCALE);
      }
      const int fb = (r >> 4) * 8 + s;
      const int l  = sub * 16 + (r & 15);
      *(uint32_t*)(Blds + fb * 2048 + half + l * 16 + b4) = o;
    }
  }
  __syncthreads();

  const int sc1 = 0x7F7F7F7F;   // e8m0 127 = 2^0 -> scale 1.0
  const uint8_t* pA = XqT + lane * 32;          // + panel*PANB + s*FRAGB
  const uint8_t* pB = Blds + lane * 16;         // + (p*8+s)*2048 (+1024 hi)
  float* myPse = Pse + (size_t)bid * T_TOK;
  float* myPsl = Psl + (size_t)bid * T_TOK;

  // ---- phase 2: m-loop (no barriers, no atomics) ----
  for (int mt = 0; mt < mloops; mt++) {
    // wave w owns token panels (mt*8 + w*2) and (mt*8 + w*2 + 1)
    const size_t mb = (size_t)(mt * 8 + w * 2) * PANB;

    i32x8 a0[2], a1[2], B0[4], B1[4];
    #pragma unroll
    for (int i = 0; i < 2; i++) a0[i] = ld32(pA + mb + (size_t)i * PANB);  // s=0
    #pragma unroll
    for (int i = 0; i < 4; i++) B0[i] = ld_lds(pB + (i * 8) * 2048);       // s=0

    f32x4 acc[2][4];
    #pragma unroll
    for (int mi = 0; mi < 2; mi++)
      #pragma unroll
      for (int ni = 0; ni < 4; ni++) { f32x4 z = {0.f, 0.f, 0.f, 0.f}; acc[mi][ni] = z; }

    #pragma unroll
    for (int s = 0; s < NKS; s += 2) {
      // prefetch step s+1
      #pragma unroll
      for (int i = 0; i < 4; i++) B1[i] = ld_lds(pB + (i * 8 + s + 1) * 2048);
      #pragma unroll
      for (int i = 0; i < 2; i++)
        a1[i] = ld32(pA + mb + (size_t)i * PANB + (s + 1) * FRAGB);
      #pragma unroll
      for (int mi = 0; mi < 2; mi++)
        #pragma unroll
        for (int ni = 0; ni < 4; ni++)
          acc[mi][ni] = __builtin_amdgcn_mfma_scale_f32_16x16x128_f8f6f4(
              a0[mi], B0[ni], acc[mi][ni], 0, 0, 0, sc1, 0, sc1);
      // prefetch step s+2 (none past the last step: no cross-iter liveness)
      if (s + 2 < NKS) {
        #pragma unroll
        for (int i = 0; i < 4; i++) B0[i] = ld_lds(pB + (i * 8 + s + 2) * 2048);
        #pragma unroll
        for (int i = 0; i < 2; i++)
          a0[i] = ld32(pA + mb + (size_t)i * PANB + (s + 2) * FRAGB);
      }
      #pragma unroll
      for (int mi = 0; mi < 2; mi++)
        #pragma unroll
        for (int ni = 0; ni < 4; ni++)
          acc[mi][ni] = __builtin_amdgcn_mfma_scale_f32_16x16x128_f8f6f4(
              a1[mi], B1[ni], acc[mi][ni], 0, 0, 0, sc1, 0, sc1);
    }

    // keep the MFMA region clean: nothing from the epilogue (or later
    // iterations) may be scheduled up into the K-loop.
    __builtin_amdgcn_sched_barrier(0);

    // ---- epilogue (per mi, small live set): D col(vocab)=l15 in panel ni,
    // row(token) = quad*4 + r within the 16-row m-frag. ----
    #pragma unroll
    for (int mi = 0; mi < 2; mi++) {
      const int trow = mt * 128 + w * 32 + mi * 16 + quad * 4;  // first of 4
      const int4 t4 = *(const int4*)&tgtc[trow];
      const int tg[4] = {t4.x, t4.y, t4.z, t4.w};
      float rse[4] = {0.f, 0.f, 0.f, 0.f};
      float rsl[4] = {0.f, 0.f, 0.f, 0.f};
      #pragma unroll
      for (int ni = 0; ni < 4; ni++) {
        const int vcol = v0 + ni * 16 + l15;
        if (vcol < VOC) {
          #pragma unroll
          for (int r = 0; r < 4; r++) {
            const float x = acc[mi][ni][r] * INV_WSCALE;
            rse[r] += __expf(x);
            rsl[r] += x;
            if (vcol == tg[r]) tlog[trow + r] = x;
          }
        }
      }
      #pragma unroll
      for (int off = 1; off < 16; off <<= 1)
        #pragma unroll
        for (int r = 0; r < 4; r++) {
          rse[r] += __shfl_xor(rse[r], off, 16);
          rsl[r] += __shfl_xor(rsl[r], off, 16);
        }
      if (l15 == 0) {
        *(float4*)&myPse[trow] = make_float4(rse[0], rse[1], rse[2], rse[3]);
        *(float4*)&myPsl[trow] = make_float4(rsl[0], rsl[1], rsl[2], rsl[3]);
      }
    }

    // hard iteration boundary: next iteration's loads may not hoist above
    // this point (memory clobber orders them against the epilogue stores).
    __builtin_amdgcn_sched_barrier(0);
    asm volatile("" ::: "memory");
  }
}

// ---------------------------------------------------------------- kernel R:
// column-reduce the 786 per-block partials -> 8 slice-partials. 2D grid
// (16 x 8): block (x,y) sums its ~98 b-rows for 256 tokens (coalesced).
__global__ void k_red(const int* __restrict__ hdr, const float* __restrict__ Pse,
                      const float* __restrict__ Psl, float* __restrict__ Se8,
                      float* __restrict__ Sl8) {
  const int t = blockIdx.x * 256 + threadIdx.x;
  const int y = blockIdx.y;
  const int b0 = (y * NBLK) / RSL;
  const int b1 = ((y + 1) * NBLK) / RSL;
  float se = 0.f, sl = 0.f;
  #pragma unroll 4
  for (int b = b0; b < b1; b++) {
    se += Pse[(size_t)b * T_TOK + t];
    sl += Psl[(size_t)b * T_TOK + t];
  }
  Se8[(size_t)y * T_TOK + t] = se;
  Sl8[(size_t)y * T_TOK + t] = sl;
}

// ---------------------------------------------------------------- kernel D:
// single block: per-token lse + loss reduction (sums the 8 slices inline).
__global__ void k_final(const int* __restrict__ hdr, const float* __restrict__ Se8,
                        const float* __restrict__ Sl8, const float* __restrict__ tlog,
                        float* __restrict__ out) {
  __shared__ float rn[256], rs[256];
  const int tid = threadIdx.x;
  const int nv = hdr[0];
  float nll = 0.f, slg = 0.f;
  for (int t = tid; t < nv; t += 256) {
    float se = 0.f, sl = 0.f;
    #pragma unroll
    for (int y = 0; y < RSL; y++) {
      se += Se8[(size_t)y * T_TOK + t];
      sl += Sl8[(size_t)y * T_TOK + t];
    }
    const float lse = logf(se);                 // shift-0 lse: sums ~6e4, safe
    nll += lse - tlog[t];
    slg += sl - (float)VOC * lse;
  }
  rn[tid] = nll; rs[tid] = slg;
  __syncthreads();
  for (int off = 128; off > 0; off >>= 1) {
    if (tid < off) { rn[tid] += rn[tid + off]; rs[tid] += rs[tid + off]; }
    __syncthreads();
  }
  if (tid == 0) {
    const float fnv = (float)nv;
    out[0] = 0.9f * (rn[0] / fnv) - 0.1f * (rs[0] / (fnv * (float)VOC));
  }
}

extern "C" void kernel_launch(void* const* d_in, const int* in_sizes, int n_in,
                              void* d_out, int out_size, void* d_ws, size_t ws_size,
                              hipStream_t stream) {
  const int*   targets = (const int*)d_in[0];
  const int*   masks   = (const int*)d_in[1];
  const float* X       = (const float*)d_in[2];
  const float* W       = (const float*)d_in[3];

  uint8_t* ws = (uint8_t*)d_ws;
  size_t off = 0;
  auto alloc = [&](size_t n) { size_t p = off; off += (n + 255) & ~(size_t)255; return p; };
  int*      hdr  = (int*)     (ws + alloc(256));
  int*      cidx = (int*)     (ws + alloc((size_t)T_TOK * 4));
  int*      tgtc = (int*)     (ws + alloc((size_t)T_TOK * 4));
  float*    tlog = (float*)   (ws + alloc((size_t)T_TOK * 4));
  float*    Se8  = (float*)   (ws + alloc((size_t)RSL * T_TOK * 4));
  float*    Sl8  = (float*)   (ws + alloc((size_t)RSL * T_TOK * 4));
  uint8_t*  XqT  = (uint8_t*) (ws + alloc((size_t)T_TOK * DIM));
  float*    Pse  = (float*)   (ws + alloc((size_t)NBLK * T_TOK * 4));
  float*    Psl  = (float*)   (ws + alloc((size_t)NBLK * T_TOK * 4));
  // total ~30 MB of workspace

  k_scan<<<dim3(1), dim3(256), 0, stream>>>(masks, targets, hdr, cidx, tgtc);
  k_xconv<<<dim3(T_TOK * DIM / 4 / 256), dim3(256), 0, stream>>>(X, hdr, cidx, XqT);
  k_gemm<<<dim3(NBLK), dim3(256), 0, stream>>>(XqT, W, hdr, tgtc, tlog, Pse, Psl);
  k_red<<<dim3(T_TOK / 256, RSL), dim3(256), 0, stream>>>(hdr, Pse, Psl, Se8, Sl8);
  k_final<<<dim3(1), dim3(256), 0, stream>>>(hdr, Se8, Sl8, tlog, (float*)d_out);
}